// Round 10
// baseline (123.434 us; speedup 1.0000x reference)
//
#include <hip/hip_runtime.h>
#include <math.h>

#define BATCH     128
#define N_NODES   32768
#define N_CHILD   65536
#define NNZ_TOTAL 1048576
#define LOG2E     1.44269504f

typedef __attribute__((ext_vector_type(2))) float fx2;

// ---------------------------------------------------------------------------
// Kernel A: fp8 exp table, per-column power-of-2 scale, register-resident.
// ---------------------------------------------------------------------------
__global__ __launch_bounds__(256) void exp8_kernel(
    const float* __restrict__ child_ll, unsigned char* __restrict__ ex8,
    float* __restrict__ winv) {
    const int c0 = blockIdx.x * 64;
    const int t  = threadIdx.x;
    const int cl = t & 63;
    const int q  = t >> 6;                 // batch quarter [q*32, q*32+32)

    float v[32];
    float m = -3.4e38f;
    const float* bp = child_ll + (size_t)(q * 32) * N_CHILD + c0 + cl;
#pragma unroll
    for (int j = 0; j < 32; ++j) {
        v[j] = bp[(size_t)j * N_CHILD];
        m = fmaxf(m, v[j]);
    }

    __shared__ float smx[4][64];
    __shared__ float skf[64];
    smx[q][cl] = m;
    __syncthreads();
    if (t < 64) {
        const float mm = fmaxf(fmaxf(smx[0][t], smx[1][t]),
                               fmaxf(smx[2][t], smx[3][t]));
        const int ks = 7 - (int)floorf(mm * LOG2E);   // colmax*2^ks in [128,256)
        skf[t] = (float)ks;
        winv[c0 + t] = exp2f((float)(-ks));
    }
    __syncthreads();
    const float kf = skf[cl];

    unsigned ow[8];
#pragma unroll
    for (int p = 0; p < 8; ++p) {
        const float a0 = exp2f(fmaf(v[4 * p + 0], LOG2E, kf));
        const float a1 = exp2f(fmaf(v[4 * p + 1], LOG2E, kf));
        const float a2 = exp2f(fmaf(v[4 * p + 2], LOG2E, kf));
        const float a3 = exp2f(fmaf(v[4 * p + 3], LOG2E, kf));
        unsigned u = 0;
        u = __builtin_amdgcn_cvt_pk_fp8_f32(a0, a1, u, false);
        u = __builtin_amdgcn_cvt_pk_fp8_f32(a2, a3, u, true);
        ow[p] = u;
    }

    __shared__ unsigned char sby[64 * 144];
    *(uint4*)&sby[cl * 144 + q * 32]      = *(uint4*)&ow[0];
    *(uint4*)&sby[cl * 144 + q * 32 + 16] = *(uint4*)&ow[4];
    __syncthreads();

    const int sub = t & 7, cc = t >> 3;
#pragma unroll
    for (int p = 0; p < 2; ++p) {
        const int c = cc + p * 32;
        *(uint4*)&ex8[(size_t)(c0 + c) * 128 + sub * 16] =
            *(const uint4*)&sby[c * 144 + sub * 16];
    }
}

// ---------------------------------------------------------------------------
// Kernel B: wfold[i] = exp(log_w[i]) * winv[cols[i]]  +  row_start via
// sorted-COO scan (no binary search). 4 nnz per thread, fully coalesced.
// ---------------------------------------------------------------------------
__global__ __launch_bounds__(256) void fold_scan_kernel(
    const float* __restrict__ log_w, const int* __restrict__ cols,
    const float* __restrict__ winv, const int* __restrict__ rows,
    float* __restrict__ wfold, int* __restrict__ row_start) {
    const int i = (blockIdx.x * 256 + threadIdx.x) * 4;
    const float4 lw = *(const float4*)&log_w[i];
    const int4   cc = *(const int4*)&cols[i];
    float4 o;
    o.x = expf(lw.x) * winv[cc.x];
    o.y = expf(lw.y) * winv[cc.y];
    o.z = expf(lw.z) * winv[cc.z];
    o.w = expf(lw.w) * winv[cc.w];
    *(float4*)&wfold[i] = o;

    const int4 rv = *(const int4*)&rows[i];
    const int rj[4] = {rv.x, rv.y, rv.z, rv.w};
    int prev = (i == 0) ? -1 : rows[i - 1];
#pragma unroll
    for (int j = 0; j < 4; ++j) {
        const int cur = rj[j];
        if (cur != prev)
            for (int q = prev + 1; q <= cur; ++q) row_start[q] = i + j;
        prev = cur;
    }
    if (i + 3 == NNZ_TOTAL - 1)
        for (int q = rj[3] + 1; q <= N_NODES; ++q) row_start[q] = NNZ_TOTAL;
}

// ---------------------------------------------------------------------------
// Kernel C: logzv[r] = log(sum exp(log_w[row segment])). 16 lanes/row.
// ---------------------------------------------------------------------------
__global__ __launch_bounds__(256) void logz_kernel(
    const float* __restrict__ log_w, const int* __restrict__ row_start,
    float* __restrict__ logzv) {
    const int t = threadIdx.x;
    const int g = t >> 4, j = t & 15;
    const int r = blockIdx.x * 16 + g;
    const int s = row_start[r], e = row_start[r + 1];
    float sum = 0.f;
    for (int i = s + j; i < e; i += 16) sum += expf(log_w[i]);
    sum += __shfl_xor(sum, 1, 64);
    sum += __shfl_xor(sum, 2, 64);
    sum += __shfl_xor(sum, 4, 64);
    sum += __shfl_xor(sum, 8, 64);
    if (j == 0) logzv[r] = logf(sum);
}

// ---------------------------------------------------------------------------
// Kernel D: per-row sum (R7 schedule) + COALESCED OUTPUT.
// Block = 512 threads = 8 waves, owns 32 consecutive rows; wave processes
// 4 rows sequentially (cross-row pipelining by compiler); results staged in
// a padded LDS tile; block epilogue writes out[b][r0..r0+31] as contiguous
// 128B lines (131K write requests vs 4.2M scattered).
// ---------------------------------------------------------------------------
__global__ __launch_bounds__(512, 6) void sum_rows_kernel(
    const unsigned char* __restrict__ ex8, const float* __restrict__ wfold,
    const int* __restrict__ cols, const int* __restrict__ row_start,
    const float* __restrict__ logzv, float* __restrict__ out) {
    const int tid  = threadIdx.x;
    const int wave = tid >> 6;           // 0..7
    const int lane = tid & 63;
    const int bid  = blockIdx.x;         // grid = 1024, %8==0
    const int swz  = (bid & 7) * 128 + (bid >> 3);   // XCD swizzle
    const int r0   = swz * 32;

    __shared__ float tile[32 * 130];     // [row][batch], stride 130 words

    const int slot = lane >> 3;                  // nnz slot within granule
    const int sub  = lane & 7;                   // 16B chunk within 128B row
    const unsigned boff = (unsigned)sub * 16u;
    const int sel  = lane >> 3;                  // output pair selector

#pragma unroll
    for (int i = 0; i < 4; ++i) {
        const int ridx = wave * 4 + i;
        const int r    = r0 + ridx;
        const int start = row_start[r];
        const int end   = row_start[r + 1];
        const float lz  = logzv[r];

        float acc[16];
#pragma unroll
        for (int k = 0; k < 16; ++k) acc[k] = 0.f;

        for (int base = start; base < end; base += 64) {
            const int  idx   = base + lane;
            const bool valid = idx < end;
            const int   c  = __builtin_nontemporal_load(&cols[valid ? idx : start]);
            const float wf = valid ? __builtin_nontemporal_load(&wfold[idx]) : 0.f;
            const int seg = end - base;          // wave-uniform

            int ct[8]; float wt[8]; uint4 g[8];

            // Phase A: redistribute cols+folded weights (8-nnz granules)
#pragma unroll
            for (int t8 = 0; t8 < 8; ++t8) {
                if (t8 * 8 < seg) {
                    const int pa = (t8 * 8 + slot) * 4;
                    ct[t8] = __builtin_amdgcn_ds_bpermute(pa, c);
                    wt[t8] = __uint_as_float(__builtin_amdgcn_ds_bpermute(
                        pa, __float_as_uint(wf)));
                }
            }
            // Phase B: issue all gathers (8 dwordx4 in flight, 8 nnz each)
#pragma unroll
            for (int t8 = 0; t8 < 8; ++t8) {
                if (t8 * 8 < seg)
                    g[t8] = *(const uint4*)(ex8 +
                            ((size_t)(unsigned)ct[t8] << 7) + boff);
            }
            // Phase C: consume (fp8 -> f32 packed cvt)
#pragma unroll
            for (int t8 = 0; t8 < 8; ++t8) {
                if (t8 * 8 < seg) {
                    const float wtv = wt[t8];
                    const unsigned* gu = (const unsigned*)&g[t8];
#pragma unroll
                    for (int q = 0; q < 4; ++q) {
                        const fx2 lo = __builtin_amdgcn_cvt_pk_f32_fp8((int)gu[q], false);
                        const fx2 hi = __builtin_amdgcn_cvt_pk_f32_fp8((int)gu[q], true);
                        acc[q * 4 + 0] = fmaf(wtv, lo.x, acc[q * 4 + 0]);
                        acc[q * 4 + 1] = fmaf(wtv, lo.y, acc[q * 4 + 1]);
                        acc[q * 4 + 2] = fmaf(wtv, hi.x, acc[q * 4 + 2]);
                        acc[q * 4 + 3] = fmaf(wtv, hi.y, acc[q * 4 + 3]);
                    }
                }
            }
        }

        // fold the 8 slot-groups (all lanes end up holding the totals)
#pragma unroll
        for (int k = 0; k < 16; ++k) {
            acc[k] += __shfl_xor(acc[k], 8, 64);
            acc[k] += __shfl_xor(acc[k], 16, 64);
            acc[k] += __shfl_xor(acc[k], 32, 64);
        }

        // static-index select: this lane stores batch pair (sub*16 + sel*2)
        float v0 = acc[0], v1 = acc[1];
#pragma unroll
        for (int kk = 1; kk < 8; ++kk) {
            v0 = (sel == kk) ? acc[2 * kk]     : v0;
            v1 = (sel == kk) ? acc[2 * kk + 1] : v1;
        }
        const int b = sub * 16 + sel * 2;
        const fx2 ov = { logf(v0) - lz, logf(v1) - lz };
        *(fx2*)&tile[ridx * 130 + b] = ov;
    }
    __syncthreads();

    // block epilogue: coalesced 128B-line writes of out[b][r0..r0+31]
#pragma unroll
    for (int p = 0; p < 2; ++p) {
        const int b  = (tid >> 3) + p * 64;
        const int rc = (tid & 7) * 4;
        float4 o;
        o.x = tile[(rc + 0) * 130 + b];
        o.y = tile[(rc + 1) * 130 + b];
        o.z = tile[(rc + 2) * 130 + b];
        o.w = tile[(rc + 3) * 130 + b];
        *(float4*)&out[(size_t)b * N_NODES + r0 + rc] = o;
    }
}

// ---------------------------------------------------------------------------
extern "C" void kernel_launch(void* const* d_in, const int* in_sizes, int n_in,
                              void* d_out, int out_size, void* d_ws, size_t ws_size,
                              hipStream_t stream) {
    const float* child_ll = (const float*)d_in[0];
    const float* log_w    = (const float*)d_in[1];
    const int*   rows     = (const int*)d_in[2];
    const int*   cols     = (const int*)d_in[3];
    float*       out      = (float*)d_out;

    unsigned char* ex8 = (unsigned char*)d_ws;                             // 8.4 MB
    float* winv      = (float*)((char*)d_ws + (size_t)N_CHILD * 128);      // 256 KB
    float* wfold     = (float*)((char*)winv + (size_t)N_CHILD * 4);        // 4 MB
    int*   row_start = (int*)((char*)wfold + (size_t)NNZ_TOTAL * 4);       // 128 KB
    float* logzv     = (float*)((char*)row_start + (size_t)(N_NODES + 1) * 4);

    exp8_kernel<<<N_CHILD / 64, 256, 0, stream>>>(child_ll, ex8, winv);
    fold_scan_kernel<<<NNZ_TOTAL / 1024, 256, 0, stream>>>(
        log_w, cols, winv, rows, wfold, row_start);
    logz_kernel<<<N_NODES / 16, 256, 0, stream>>>(log_w, row_start, logzv);
    sum_rows_kernel<<<1024, 512, 0, stream>>>(ex8, wfold, cols,
                                              row_start, logzv, out);
}

// Round 11
// 62.453 us; speedup vs baseline: 1.9764x; 1.9764x over previous
//
#include <hip/hip_runtime.h>
#include <math.h>

#define BATCH     128
#define N_NODES   32768
#define N_CHILD   65536
#define NNZ_TOTAL 1048576
#define LOG2E     1.44269504f

typedef __attribute__((ext_vector_type(2))) float fx2;

// ---------------------------------------------------------------------------
// Kernel A: fp8 exp table, per-column power-of-2 scale, register-resident.
// ---------------------------------------------------------------------------
__global__ __launch_bounds__(256) void exp8_kernel(
    const float* __restrict__ child_ll, unsigned char* __restrict__ ex8,
    float* __restrict__ winv) {
    const int c0 = blockIdx.x * 64;
    const int t  = threadIdx.x;
    const int cl = t & 63;
    const int q  = t >> 6;                 // batch quarter [q*32, q*32+32)

    float v[32];
    float m = -3.4e38f;
    const float* bp = child_ll + (size_t)(q * 32) * N_CHILD + c0 + cl;
#pragma unroll
    for (int j = 0; j < 32; ++j) {
        v[j] = bp[(size_t)j * N_CHILD];
        m = fmaxf(m, v[j]);
    }

    __shared__ float smx[4][64];
    __shared__ float skf[64];
    smx[q][cl] = m;
    __syncthreads();
    if (t < 64) {
        const float mm = fmaxf(fmaxf(smx[0][t], smx[1][t]),
                               fmaxf(smx[2][t], smx[3][t]));
        const int ks = 7 - (int)floorf(mm * LOG2E);   // colmax*2^ks in [128,256)
        skf[t] = (float)ks;
        winv[c0 + t] = exp2f((float)(-ks));
    }
    __syncthreads();
    const float kf = skf[cl];

    unsigned ow[8];
#pragma unroll
    for (int p = 0; p < 8; ++p) {
        const float a0 = exp2f(fmaf(v[4 * p + 0], LOG2E, kf));
        const float a1 = exp2f(fmaf(v[4 * p + 1], LOG2E, kf));
        const float a2 = exp2f(fmaf(v[4 * p + 2], LOG2E, kf));
        const float a3 = exp2f(fmaf(v[4 * p + 3], LOG2E, kf));
        unsigned u = 0;
        u = __builtin_amdgcn_cvt_pk_fp8_f32(a0, a1, u, false);
        u = __builtin_amdgcn_cvt_pk_fp8_f32(a2, a3, u, true);
        ow[p] = u;
    }

    __shared__ unsigned char sby[64 * 144];
    *(uint4*)&sby[cl * 144 + q * 32]      = *(uint4*)&ow[0];
    *(uint4*)&sby[cl * 144 + q * 32 + 16] = *(uint4*)&ow[4];
    __syncthreads();

    const int sub = t & 7, cc = t >> 3;
#pragma unroll
    for (int p = 0; p < 2; ++p) {
        const int c = cc + p * 32;
        *(uint4*)&ex8[(size_t)(c0 + c) * 128 + sub * 16] =
            *(const uint4*)&sby[c * 144 + sub * 16];
    }
}

// ---------------------------------------------------------------------------
// Kernel B: wfold[i] = exp(log_w[i]) * winv[cols[i]]  +  row_start via
// sorted-COO scan (no binary search). 4 nnz per thread, fully coalesced.
// ---------------------------------------------------------------------------
__global__ __launch_bounds__(256) void fold_scan_kernel(
    const float* __restrict__ log_w, const int* __restrict__ cols,
    const float* __restrict__ winv, const int* __restrict__ rows,
    float* __restrict__ wfold, int* __restrict__ row_start) {
    const int i = (blockIdx.x * 256 + threadIdx.x) * 4;
    const float4 lw = *(const float4*)&log_w[i];
    const int4   cc = *(const int4*)&cols[i];
    float4 o;
    o.x = expf(lw.x) * winv[cc.x];
    o.y = expf(lw.y) * winv[cc.y];
    o.z = expf(lw.z) * winv[cc.z];
    o.w = expf(lw.w) * winv[cc.w];
    *(float4*)&wfold[i] = o;

    const int4 rv = *(const int4*)&rows[i];
    const int rj[4] = {rv.x, rv.y, rv.z, rv.w};
    int prev = (i == 0) ? -1 : rows[i - 1];
#pragma unroll
    for (int j = 0; j < 4; ++j) {
        const int cur = rj[j];
        if (cur != prev)
            for (int q = prev + 1; q <= cur; ++q) row_start[q] = i + j;
        prev = cur;
    }
    if (i + 3 == NNZ_TOTAL - 1)
        for (int q = rj[3] + 1; q <= N_NODES; ++q) row_start[q] = NNZ_TOTAL;
}

// ---------------------------------------------------------------------------
// Kernel C: logzv[r] = log(sum exp(log_w[row segment])). 16 lanes/row.
// ---------------------------------------------------------------------------
__global__ __launch_bounds__(256) void logz_kernel(
    const float* __restrict__ log_w, const int* __restrict__ row_start,
    float* __restrict__ logzv) {
    const int t = threadIdx.x;
    const int g = t >> 4, j = t & 15;
    const int r = blockIdx.x * 16 + g;
    const int s = row_start[r], e = row_start[r + 1];
    float sum = 0.f;
    for (int i = s + j; i < e; i += 16) sum += expf(log_w[i]);
    sum += __shfl_xor(sum, 1, 64);
    sum += __shfl_xor(sum, 2, 64);
    sum += __shfl_xor(sum, 4, 64);
    sum += __shfl_xor(sum, 8, 64);
    if (j == 0) logzv[r] = logf(sum);
}

// ---------------------------------------------------------------------------
// Kernel D: per-row sum, one wave per row — R7's measured-best schedule
// (64-nnz tile, bpermute meta redistribution, 8 dwordx4 gathers in flight,
// shfl-fold epilogue) minus the log_w/expf/wsum work (logz precomputed).
// ---------------------------------------------------------------------------
__global__ __launch_bounds__(256, 4) void sum_rows_kernel(
    const unsigned char* __restrict__ ex8, const float* __restrict__ wfold,
    const int* __restrict__ cols, const int* __restrict__ row_start,
    const float* __restrict__ logzv, float* __restrict__ out) {
    const int wave = threadIdx.x >> 6;   // 0..3
    const int lane = threadIdx.x & 63;
    const int bid  = blockIdx.x;         // grid = 8192
    const int rb   = (bid & 7) * (N_NODES / 4 / 8) + (bid >> 3);
    const int r    = rb * 4 + wave;

    const int start = row_start[r];
    const int end   = row_start[r + 1];
    const int  slot = lane >> 3;                   // nnz slot within granule
    const unsigned sub = (unsigned)lane & 7u;      // 16B chunk within 128B row
    const unsigned boff = sub * 16u;

    float acc[16];
#pragma unroll
    for (int k = 0; k < 16; ++k) acc[k] = 0.f;

    for (int base = start; base < end; base += 64) {
        const int  idx   = base + lane;
        const bool valid = idx < end;
        const int   c  = __builtin_nontemporal_load(&cols[valid ? idx : start]);
        const float wf = valid ? __builtin_nontemporal_load(&wfold[idx]) : 0.f;
        const int seg = end - base;                // wave-uniform

        int   ct[8];
        float wt[8];
        uint4 g[8];

        // Phase A: redistribute cols+folded weights (8-nnz granules)
#pragma unroll
        for (int t8 = 0; t8 < 8; ++t8) {
            if (t8 * 8 < seg) {
                const int pa = (t8 * 8 + slot) * 4;
                ct[t8] = __builtin_amdgcn_ds_bpermute(pa, c);
                wt[t8] = __uint_as_float(__builtin_amdgcn_ds_bpermute(
                    pa, __float_as_uint(wf)));
            }
        }
        // Phase B: issue all gathers (8 dwordx4 in flight, 8 nnz each)
#pragma unroll
        for (int t8 = 0; t8 < 8; ++t8) {
            if (t8 * 8 < seg)
                g[t8] = *(const uint4*)(ex8 +
                        ((size_t)(unsigned)ct[t8] << 7) + boff);
        }
        // Phase C: consume (fp8 -> f32 via packed HW cvt)
#pragma unroll
        for (int t8 = 0; t8 < 8; ++t8) {
            if (t8 * 8 < seg) {
                const float wtv = wt[t8];
                const unsigned* gu = (const unsigned*)&g[t8];
#pragma unroll
                for (int q = 0; q < 4; ++q) {
                    const fx2 lo = __builtin_amdgcn_cvt_pk_f32_fp8((int)gu[q], false);
                    const fx2 hi = __builtin_amdgcn_cvt_pk_f32_fp8((int)gu[q], true);
                    acc[q * 4 + 0] = fmaf(wtv, lo.x, acc[q * 4 + 0]);
                    acc[q * 4 + 1] = fmaf(wtv, lo.y, acc[q * 4 + 1]);
                    acc[q * 4 + 2] = fmaf(wtv, hi.x, acc[q * 4 + 2]);
                    acc[q * 4 + 3] = fmaf(wtv, hi.y, acc[q * 4 + 3]);
                }
            }
        }
    }

    // fold the 8 slot-groups (same batch samples) together
#pragma unroll
    for (int k = 0; k < 16; ++k) {
        acc[k] += __shfl_xor(acc[k], 8, 64);
        acc[k] += __shfl_xor(acc[k], 16, 64);
        acc[k] += __shfl_xor(acc[k], 32, 64);
    }

    if (lane < 8) {
        const float lz = logzv[r];
        const int b0 = lane * 16;
#pragma unroll
        for (int k = 0; k < 16; ++k)
            out[(size_t)(b0 + k) * N_NODES + r] = logf(acc[k]) - lz;
    }
}

// ---------------------------------------------------------------------------
extern "C" void kernel_launch(void* const* d_in, const int* in_sizes, int n_in,
                              void* d_out, int out_size, void* d_ws, size_t ws_size,
                              hipStream_t stream) {
    const float* child_ll = (const float*)d_in[0];
    const float* log_w    = (const float*)d_in[1];
    const int*   rows     = (const int*)d_in[2];
    const int*   cols     = (const int*)d_in[3];
    float*       out      = (float*)d_out;

    unsigned char* ex8 = (unsigned char*)d_ws;                             // 8.4 MB
    float* winv      = (float*)((char*)d_ws + (size_t)N_CHILD * 128);      // 256 KB
    float* wfold     = (float*)((char*)winv + (size_t)N_CHILD * 4);        // 4 MB
    int*   row_start = (int*)((char*)wfold + (size_t)NNZ_TOTAL * 4);       // 128 KB
    float* logzv     = (float*)((char*)row_start + (size_t)(N_NODES + 1) * 4);

    exp8_kernel<<<N_CHILD / 64, 256, 0, stream>>>(child_ll, ex8, winv);
    fold_scan_kernel<<<NNZ_TOTAL / 1024, 256, 0, stream>>>(
        log_w, cols, winv, rows, wfold, row_start);
    logz_kernel<<<N_NODES / 16, 256, 0, stream>>>(log_w, row_start, logzv);
    sum_rows_kernel<<<N_NODES / 4, 256, 0, stream>>>(ex8, wfold, cols,
                                                     row_start, logzv, out);
}